// Round 3
// baseline (837.989 us; speedup 1.0000x reference)
//
#include <hip/hip_runtime.h>
#include <math.h>

#define NN 512
#define HH 256
#define BB 32
#define NE 130816

typedef unsigned short ushort_t;
typedef unsigned int u32;
using short8  = __attribute__((ext_vector_type(8))) short;
using floatx4 = __attribute__((ext_vector_type(4))) float;

typedef __attribute__((address_space(3))) u32* lds_u32p;
typedef const __attribute__((address_space(1))) u32* glb_u32p;

// ---------- bf16 helpers (RNE) ----------
__device__ inline unsigned short f2bf(float f) {
    unsigned int u = __float_as_uint(f);
    unsigned int r = (u + 0x7fffu + ((u >> 16) & 1u)) >> 16;
    return (unsigned short)r;
}
__device__ inline float bf2f(unsigned short x) {
    return __uint_as_float(((unsigned int)x) << 16);
}

// ---------- reduction helpers ----------
__device__ inline float wave_reduce_sum(float v) {
#pragma unroll
    for (int o = 32; o > 0; o >>= 1) v += __shfl_xor(v, o, 64);
    return v;
}
__device__ inline float block_reduce_sum256(float v, float* red) {
    v = wave_reduce_sum(v);
    int w = threadIdx.x >> 6;
    if ((threadIdx.x & 63) == 0) red[w] = v;
    __syncthreads();
    v = red[0] + red[1] + red[2] + red[3];
    __syncthreads();
    return v;
}

// ---------- 1) schedule init + out zero ----------
__global__ void init_kernel(float* __restrict__ sched, float* __restrict__ out) {
    __shared__ float alpha_s[100];
    int tid = threadIdx.x;
    if (tid < 100) {
        const double PI_H = 3.14159265358979323846 * 0.5;
        double f1 = (((double)tid / 100.0) + 0.008) / 1.008 * PI_H;
        double f2 = (((double)(tid + 1) / 100.0) + 0.008) / 1.008 * PI_H;
        double c1 = cos(f1), c2 = cos(f2);
        double beta = 1.0 - (c2 * c2) / (c1 * c1);
        if (beta > 0.999) beta = 0.999;
        alpha_s[tid] = 1.0f - (float)beta;
    }
    __syncthreads();
    if (tid == 0) {
        out[0] = 0.0f;
        float cum = 1.0f;
        for (int k = 0; k < 100; k++) {
            cum *= alpha_s[k];
            sched[k]       = sqrtf(cum);
            sched[100 + k] = sqrtf(1.0f - cum);
        }
    }
}

// ---------- 2) t_emb and per-layer t_bias ----------
__global__ __launch_bounds__(256) void temb_kernel(
    const float* __restrict__ te_W1, const float* __restrict__ te_b1,
    const float* __restrict__ te_W2, const float* __restrict__ te_b2,
    const float* __restrict__ tp_W,  const float* __restrict__ tp_b,
    const int* __restrict__ t, float* __restrict__ tbias_out) {
    int b = blockIdx.x, tid = threadIdx.x;
    __shared__ float hid[HH], emb[HH];
    float tf = (float)t[b] / 100.0f;
    float z = tf * te_W1[tid] + te_b1[tid];
    hid[tid] = z / (1.0f + expf(-z));
    __syncthreads();
    float acc = te_b2[tid];
#pragma unroll 8
    for (int k = 0; k < HH; k++) acc = fmaf(hid[k], te_W2[k * HH + tid], acc);
    emb[tid] = acc;
    __syncthreads();
    for (int l = 0; l < 4; l++) {
        const float* W = tp_W + l * HH * HH;
        float a2 = tp_b[l * HH + tid];
#pragma unroll 8
        for (int k = 0; k < HH; k++) a2 = fmaf(emb[k], W[k * HH + tid], a2);
        tbias_out[l * (BB * HH) + b * HH + tid] = a2;
    }
}

// ---------- 3) adj_t (bf16) + inverse row abs-sum (fp32) ----------
__global__ __launch_bounds__(256) void adj_kernel(
    const float* __restrict__ adj0, const float* __restrict__ noise,
    const int* __restrict__ t, const float* __restrict__ sched,
    ushort_t* __restrict__ adjt_bf, float* __restrict__ invrs) {
    __shared__ float red[4];
    const int bid = blockIdx.x;          // b*512 + i
    const int b = bid >> 9;
    const int ts = t[b];
    const float sab = sched[ts], som = sched[100 + ts];
    const size_t base = (size_t)bid * NN;
    const int tid = threadIdx.x;
    float s = 0.0f;
#pragma unroll
    for (int jj = 0; jj < 2; jj++) {
        int j = tid + jj * 256;
        float a = sab * adj0[base + j] + som * noise[base + j];
        adjt_bf[base + j] = f2bf(a);
        s += fabsf(a);
    }
    s = block_reduce_sum256(s, red);
    if (tid == 0) invrs[bid] = 1.0f / (s + 1.0f);
}

// ---------- 4) weight transpose+convert: W (RxC f32) -> WT (CxR bf16) ----------
__global__ __launch_bounds__(256) void wcvt_kernel(
    const float* __restrict__ ip_W, const float* __restrict__ msg_W,
    const float* __restrict__ upd_W,
    ushort_t* __restrict__ ipWT, ushort_t* __restrict__ msgWT,
    ushort_t* __restrict__ updWT) {
    const int z = blockIdx.z;
    const float* src; ushort_t* dst; int R;
    if (z == 0)      { src = ip_W;                          dst = ipWT;                       R = 512; }
    else if (z <= 4) { src = msg_W + (z - 1) * 65536;       dst = msgWT + (z - 1) * 65536;    R = 256; }
    else             { src = upd_W + (z - 5) * 131072;      dst = updWT + (z - 5) * 131072;   R = 512; }
    const int r0 = blockIdx.y * 32, c0 = blockIdx.x * 32;
    if (r0 >= R) return;
    __shared__ float T[32][33];
    const int tr = threadIdx.x >> 5, tc = threadIdx.x & 31;
#pragma unroll
    for (int s = 0; s < 32; s += 8)
        T[tr + s][tc] = src[(size_t)(r0 + tr + s) * 256 + c0 + tc];
    __syncthreads();
#pragma unroll
    for (int s = 0; s < 32; s += 8)
        dst[(size_t)(c0 + tr + s) * R + r0 + tc] = f2bf(T[tc][tr + s]);
}

// ---------- 5) bf16 transpose: hm (b,512,256) -> hmT (b,256,512) ----------
__global__ __launch_bounds__(256) void tpose_kernel(
    const ushort_t* __restrict__ src, ushort_t* __restrict__ dst) {
    const int b = blockIdx.z;
    const int j0 = blockIdx.y * 32, h0 = blockIdx.x * 32;
    const ushort_t* s = src + (size_t)b * NN * HH;
    ushort_t* d = dst + (size_t)b * NN * HH;
    __shared__ ushort_t T[32][34];
    const int tr = threadIdx.x >> 5, tc = threadIdx.x & 31;
#pragma unroll
    for (int ss = 0; ss < 32; ss += 8)
        T[tr + ss][tc] = s[(size_t)(j0 + tr + ss) * HH + h0 + tc];
    __syncthreads();
#pragma unroll
    for (int ss = 0; ss < 32; ss += 8)
        d[(size_t)(h0 + tr + ss) * NN + j0 + tc] = T[tc][tr + ss];
}

// ---------- 6) bf16 MFMA GEMM (m97 structure): C(Mx256) = A(MxK) @ B + epilogue ----------
// Tile 128x128, 4 waves (2x2), each wave 64x64 = 4x4 MFMA 16x16x32.
// Staging via global_load_lds width=16 with XOR-swizzled LDS chunks:
//   LDS row r (64B = 4 chunks of 16B); chunk c holds global k-chunk c ^ ((r>>2)&3).
//   Frag reads then hit all 32 banks at 2-way (free). DMA deposit is lane-ordered.
// B supplied TRANSPOSED: BT[n][k], leading dim ldbt; bstride per 512-row batch.
// A2 non-null => A switches to A2 at k=256 (concat GEMM).
__global__ __launch_bounds__(256) void gemm_bf16(
    int K,
    const ushort_t* __restrict__ A, int lda, const ushort_t* __restrict__ A2,
    const ushort_t* __restrict__ BT, int ldbt, long long bstride,
    const float* __restrict__ bias, const float* __restrict__ scale,
    const float* __restrict__ tbias, const ushort_t* __restrict__ resid,
    float* __restrict__ Cf, ushort_t* __restrict__ Cb) {
    __shared__ ushort_t As[128 * 32];
    __shared__ ushort_t Bs[128 * 32];
    const int row0 = blockIdx.x * 128;
    const int n0 = blockIdx.y * 128;
    const int tid = threadIdx.x;
    const int lane = tid & 63;
    const int w = tid >> 6;
    const int l15 = lane & 15, quad = lane >> 4;
    const int wm = (w >> 1) * 64, wn = (w & 1) * 64;
    const ushort_t* Bp = BT + (size_t)(row0 >> 9) * (size_t)bstride;

    // staging: lane l of wave w (round r) deposits 16B at LDS rows (r*4+w)*16 + (l>>2)
    const int srow = lane >> 2;                               // row within 16-row chunk
    const int gkoff = (((lane & 3) ^ (lane >> 4)) << 3);      // swizzled global k-offset (ushorts)
    // frag read k-offset: chunk = quad ^ ((row>>2)&3), row%16 == l15
    const int swz = ((quad ^ ((l15 >> 2) & 3)) << 3);

    floatx4 acc[4][4];
#pragma unroll
    for (int i = 0; i < 4; i++)
#pragma unroll
        for (int j = 0; j < 4; j++) {
            acc[i][j][0] = 0.0f; acc[i][j][1] = 0.0f;
            acc[i][j][2] = 0.0f; acc[i][j][3] = 0.0f;
        }

    for (int kc = 0; kc < K; kc += 32) {
        const ushort_t* Ause = A; int kk = kc;
        if (A2 && kc >= 256) { Ause = A2; kk = kc - 256; }
#pragma unroll
        for (int r = 0; r < 2; r++) {
            const int lbase = (r * 4 + w) * 16;
            const ushort_t* gpA = Ause + (size_t)(row0 + lbase + srow) * lda + kk + gkoff;
            __builtin_amdgcn_global_load_lds((glb_u32p)(const void*)gpA,
                                             (lds_u32p)(void*)&As[lbase * 32], 16, 0, 0);
            const ushort_t* gpB = Bp + (size_t)(n0 + lbase + srow) * ldbt + kc + gkoff;
            __builtin_amdgcn_global_load_lds((glb_u32p)(const void*)gpB,
                                             (lds_u32p)(void*)&Bs[lbase * 32], 16, 0, 0);
        }
        __syncthreads();

        short8 af[4], bfr[4];
#pragma unroll
        for (int tm = 0; tm < 4; tm++)
            af[tm] = *(const short8*)&As[(wm + tm * 16 + l15) * 32 + swz];
#pragma unroll
        for (int tn = 0; tn < 4; tn++)
            bfr[tn] = *(const short8*)&Bs[(wn + tn * 16 + l15) * 32 + swz];
#pragma unroll
        for (int tm = 0; tm < 4; tm++)
#pragma unroll
            for (int tn = 0; tn < 4; tn++)
                acc[tm][tn] = __builtin_amdgcn_mfma_f32_16x16x32_bf16(
                    af[tm], bfr[tn], acc[tm][tn], 0, 0, 0);
        __syncthreads();
    }

#pragma unroll
    for (int tm = 0; tm < 4; tm++)
#pragma unroll
        for (int tn = 0; tn < 4; tn++) {
#pragma unroll
            for (int r = 0; r < 4; r++) {
                const int row = row0 + wm + tm * 16 + quad * 4 + r;
                const int col = n0 + wn + tn * 16 + l15;
                float v = acc[tm][tn][r];
                if (scale) v *= scale[row];
                if (bias) v += bias[col];
                if (tbias) v += tbias[((row >> 9) << 8) + col] + bf2f(resid[(size_t)row * HH + col]);
                if (Cf) Cf[(size_t)row * HH + col] = v;
                if (Cb) Cb[(size_t)row * HH + col] = f2bf(v);
            }
        }
}

// ---------- 7) layernorm: h_bf = bf16(LN(pre) * g + b) ----------
__global__ __launch_bounds__(256) void ln_kernel(
    const float* __restrict__ pre, const float* __restrict__ g,
    const float* __restrict__ b, ushort_t* __restrict__ h_bf) {
    __shared__ float red[4];
    const size_t base = (size_t)blockIdx.x * HH;
    const int tid = threadIdx.x;
    float x = pre[base + tid];
    float mu = block_reduce_sum256(x, red) * (1.0f / HH);
    float d = x - mu;
    float var = block_reduce_sum256(d * d, red) * (1.0f / HH);
    h_bf[base + tid] = f2bf(d * rsqrtf(var + 1e-5f) * g[tid] + b[tid]);
}

// ---------- 8) partial h_graph sums ----------
__global__ __launch_bounds__(256) void psum_kernel(
    const ushort_t* __restrict__ h_bf, float* __restrict__ partial) {
    const int b = blockIdx.x, ch = blockIdx.y, tid = threadIdx.x;
    const ushort_t* hp = h_bf + ((size_t)b * NN + ch * 32) * HH;
    float s = 0.0f;
#pragma unroll
    for (int i = 0; i < 32; i++) s += bf2f(hp[i * HH + tid]);
    partial[(((size_t)b * 16 + ch) << 8) + tid] = s;
}

// ---------- 9) h_graph reduce + first proj + silu -> sT[h][b] (transposed!) ----------
__global__ __launch_bounds__(256) void final_kernel(
    const float* __restrict__ partial, const float* __restrict__ op_W1,
    const float* __restrict__ op_b1, float* __restrict__ sT) {
    int b = blockIdx.x, tid = threadIdx.x;
    __shared__ float hg[HH];
    float acc = 0.0f;
#pragma unroll
    for (int c = 0; c < 16; c++) acc += partial[(((size_t)b * 16 + c) << 8) + tid];
    hg[tid] = acc;
    __syncthreads();
    float o = op_b1[tid];
#pragma unroll 8
    for (int k = 0; k < HH; k++) o = fmaf(hg[k], op_W1[k * HH + tid], o);
    sT[tid * BB + b] = o / (1.0f + expf(-o));   // [h][b] layout for scalar loads
}

// ---------- 10) fused second proj + triu target + MSE ----------
// 1 edge per thread; sT rows are wave-uniform -> scalar (SGPR) loads;
// vector pipe: 1 coalesced w2 load + 32 FMA per h. Grid 511 = 2 blocks/CU.
__global__ __launch_bounds__(256) void loss_kernel(
    const float* __restrict__ sT, const float* __restrict__ op_W2,
    const float* __restrict__ op_b2, const float* __restrict__ noise,
    float* __restrict__ out) {
    __shared__ float red[4];
    const int tid = threadIdx.x;
    const int e = blockIdx.x * 256 + tid;
    float lsum = 0.0f;
    {
        float acc[32];
#pragma unroll
        for (int b = 0; b < 32; b++) acc[b] = 0.0f;
        const float* w2 = op_W2 + e;
#pragma unroll 4
        for (int h = 0; h < 256; h++) {
            float wv = w2[(size_t)h * NE];
            const float* sr = sT + h * BB;   // block-uniform address -> s_load
#pragma unroll
            for (int b = 0; b < 32; b++) acc[b] = fmaf(sr[b], wv, acc[b]);
        }
        // e -> (i,j) upper-triangular
        int i = (int)((1023.0 - sqrt(1046529.0 - 8.0 * (double)e)) * 0.5);
        if (i < 0) i = 0;
        if (i > 510) i = 510;
        while (i > 0 && (i * (1023 - i)) / 2 > e) --i;
        while (((i + 1) * (1022 - i)) / 2 <= e) ++i;
        int j = i + 1 + (e - (i * (1023 - i)) / 2);
        const float pb = op_b2[e];
        const float* np = noise + (size_t)i * NN + j;
#pragma unroll
        for (int b = 0; b < 32; b++) {
            float d = acc[b] + pb - np[(size_t)b * NN * NN];
            lsum += d * d;
        }
    }
    lsum *= (1.0f / (32.0f * (float)NE));
    lsum = block_reduce_sum256(lsum, red);
    if (tid == 0) atomicAdd(out, lsum);
}

// ---------- launch ----------
extern "C" void kernel_launch(void* const* d_in, const int* in_sizes, int n_in,
                              void* d_out, int out_size, void* d_ws, size_t ws_size,
                              hipStream_t stream) {
    const float* adj0  = (const float*)d_in[0];
    const float* noise = (const float*)d_in[1];
    const float* te_W1 = (const float*)d_in[2];
    const float* te_b1 = (const float*)d_in[3];
    const float* te_W2 = (const float*)d_in[4];
    const float* te_b2 = (const float*)d_in[5];
    const float* ip_W  = (const float*)d_in[6];
    const float* ip_b  = (const float*)d_in[7];
    const float* msg_W = (const float*)d_in[8];
    const float* msg_b = (const float*)d_in[9];
    const float* upd_W = (const float*)d_in[10];
    const float* upd_b = (const float*)d_in[11];
    const float* ln_g  = (const float*)d_in[12];
    const float* ln_b  = (const float*)d_in[13];
    const float* tp_W  = (const float*)d_in[14];
    const float* tp_b  = (const float*)d_in[15];
    const float* op_W1 = (const float*)d_in[16];
    const float* op_b1 = (const float*)d_in[17];
    const float* op_W2 = (const float*)d_in[18];
    const float* op_b2 = (const float*)d_in[19];
    const int*   t     = (const int*)d_in[20];
    float* out = (float*)d_out;

    float* ws = (float*)d_ws;
    float* sched   = ws;                    // 256
    float* tbias   = ws + 256;              // 32768
    float* invrs   = ws + 33024;            // 16384
    float* sbuf    = ws + 49408;            // 8192 (sT: 256x32)
    float* partial = ws + 57600;            // 131072
    float* pre     = ws + 188672;           // 4194304
    ushort_t* bfb  = (ushort_t*)(ws + 4382976);
    ushort_t* adjt_bf = bfb;                // 8388608 ushorts
    ushort_t* h_bf    = bfb + 8388608;      // 4194304
    ushort_t* msg_bf  = bfb + 12582912;     // 4194304
    ushort_t* hm_bf   = bfb + 16777216;     // 4194304
    ushort_t* hmT_bf  = bfb + 20971520;     // 4194304
    ushort_t* ipWT    = bfb + 25165824;     // 131072
    ushort_t* msgWT   = bfb + 25296896;     // 262144
    ushort_t* updWT   = bfb + 25559040;     // 524288

    init_kernel<<<1, 128, 0, stream>>>(sched, out);
    wcvt_kernel<<<dim3(8, 16, 9), 256, 0, stream>>>(ip_W, msg_W, upd_W, ipWT, msgWT, updWT);
    temb_kernel<<<32, 256, 0, stream>>>(te_W1, te_b1, te_W2, te_b2, tp_W, tp_b, t, tbias);
    adj_kernel<<<BB * NN, 256, 0, stream>>>(adj0, noise, t, sched, adjt_bf, invrs);

    dim3 ggrid(128, 2);   // M=16384/128, N=256/128
    // h = bf16(adj_t @ ip_W + ip_b)
    gemm_bf16<<<ggrid, 256, 0, stream>>>(512, adjt_bf, 512, nullptr,
                                         ipWT, 512, 0,
                                         ip_b, nullptr, nullptr, nullptr,
                                         nullptr, h_bf);
    for (int l = 0; l < 4; l++) {
        // hm = bf16(h @ msg_W[l] + msg_b[l])
        gemm_bf16<<<ggrid, 256, 0, stream>>>(256, h_bf, 256, nullptr,
                                             msgWT + l * 65536, 256, 0,
                                             msg_b + l * HH, nullptr, nullptr, nullptr,
                                             nullptr, hm_bf);
        // hmT[b] = hm[b]^T
        tpose_kernel<<<dim3(8, 16, 32), 256, 0, stream>>>(hm_bf, hmT_bf);
        // msg = bf16(rowscale * (adj_t @ hm[b]))
        gemm_bf16<<<ggrid, 256, 0, stream>>>(512, adjt_bf, 512, nullptr,
                                             hmT_bf, 512, (long long)(HH * NN),
                                             nullptr, invrs, nullptr, nullptr,
                                             nullptr, msg_bf);
        // pre = h@updW[:256] + msg@updW[256:] + upd_b + t_bias + h
        gemm_bf16<<<ggrid, 256, 0, stream>>>(512, h_bf, 256, msg_bf,
                                             updWT + l * 131072, 512, 0,
                                             upd_b + l * HH, nullptr,
                                             tbias + l * BB * HH, h_bf,
                                             pre, nullptr);
        // h = bf16(LN(pre)*g + b)
        ln_kernel<<<BB * NN, 256, 0, stream>>>(pre, ln_g + l * HH, ln_b + l * HH, h_bf);
    }
    psum_kernel<<<dim3(32, 16), 256, 0, stream>>>(h_bf, partial);
    final_kernel<<<32, 256, 0, stream>>>(partial, op_W1, op_b1, sbuf);
    loss_kernel<<<511, 256, 0, stream>>>(sbuf, op_W2, op_b2, noise, out);
}

// Round 4
// 632.030 us; speedup vs baseline: 1.3259x; 1.3259x over previous
//
#include <hip/hip_runtime.h>
#include <math.h>

#define NN 512
#define HH 256
#define BB 32
#define NE 130816

typedef unsigned short ushort_t;
typedef unsigned int u32;
using short8  = __attribute__((ext_vector_type(8))) short;
using floatx4 = __attribute__((ext_vector_type(4))) float;

typedef __attribute__((address_space(3))) u32* lds_u32p;
typedef const __attribute__((address_space(1))) u32* glb_u32p;

// ---------- bf16 helpers (RNE) ----------
__device__ inline unsigned short f2bf(float f) {
    unsigned int u = __float_as_uint(f);
    unsigned int r = (u + 0x7fffu + ((u >> 16) & 1u)) >> 16;
    return (unsigned short)r;
}
__device__ inline float bf2f(unsigned short x) {
    return __uint_as_float(((unsigned int)x) << 16);
}

// ---------- reduction helpers ----------
__device__ inline float wave_reduce_sum(float v) {
#pragma unroll
    for (int o = 32; o > 0; o >>= 1) v += __shfl_xor(v, o, 64);
    return v;
}
__device__ inline float block_reduce_sum256(float v, float* red) {
    v = wave_reduce_sum(v);
    int w = threadIdx.x >> 6;
    if ((threadIdx.x & 63) == 0) red[w] = v;
    __syncthreads();
    v = red[0] + red[1] + red[2] + red[3];
    __syncthreads();
    return v;
}

// ---------- 1) schedule init + out zero ----------
__global__ void init_kernel(float* __restrict__ sched, float* __restrict__ out) {
    __shared__ float alpha_s[100];
    int tid = threadIdx.x;
    if (tid < 100) {
        const double PI_H = 3.14159265358979323846 * 0.5;
        double f1 = (((double)tid / 100.0) + 0.008) / 1.008 * PI_H;
        double f2 = (((double)(tid + 1) / 100.0) + 0.008) / 1.008 * PI_H;
        double c1 = cos(f1), c2 = cos(f2);
        double beta = 1.0 - (c2 * c2) / (c1 * c1);
        if (beta > 0.999) beta = 0.999;
        alpha_s[tid] = 1.0f - (float)beta;
    }
    __syncthreads();
    if (tid == 0) {
        out[0] = 0.0f;
        float cum = 1.0f;
        for (int k = 0; k < 100; k++) {
            cum *= alpha_s[k];
            sched[k]       = sqrtf(cum);
            sched[100 + k] = sqrtf(1.0f - cum);
        }
    }
}

// ---------- 2a) emb = silu(tf@W1+b1)@W2 + b2 ; grid (32 b, 4 colblk) ----------
__global__ __launch_bounds__(256) void temb1_kernel(
    const float* __restrict__ te_W1, const float* __restrict__ te_b1,
    const float* __restrict__ te_W2, const float* __restrict__ te_b2,
    const int* __restrict__ t, float* __restrict__ emb_out) {
    const int b = blockIdx.x, cb = blockIdx.y * 64, tid = threadIdx.x;
    __shared__ float hid[HH];
    __shared__ float part[4][64];
    float tf = (float)t[b] / 100.0f;
    float z = tf * te_W1[tid] + te_b1[tid];
    hid[tid] = z / (1.0f + expf(-z));
    __syncthreads();
    const int col = tid & 63, kc = tid >> 6;
    float a = 0.0f;
#pragma unroll 8
    for (int k0 = 0; k0 < 64; k0++) {
        int k = kc * 64 + k0;
        a = fmaf(hid[k], te_W2[k * HH + cb + col], a);
    }
    part[kc][col] = a;
    __syncthreads();
    if (kc == 0) {
        float o = part[0][col] + part[1][col] + part[2][col] + part[3][col] + te_b2[cb + col];
        emb_out[b * HH + cb + col] = o;
    }
}

// ---------- 2b) tbias[l,b,:] = emb[b]@tp_W[l] + tp_b[l] ; grid (32 b, 16) ----------
__global__ __launch_bounds__(256) void temb2_kernel(
    const float* __restrict__ emb, const float* __restrict__ tp_W,
    const float* __restrict__ tp_b, float* __restrict__ tbias_out) {
    const int b = blockIdx.x;
    const int l = blockIdx.y >> 2, cb = (blockIdx.y & 3) * 64;
    const int tid = threadIdx.x;
    __shared__ float es[HH];
    __shared__ float part[4][64];
    es[tid] = emb[b * HH + tid];
    __syncthreads();
    const int col = tid & 63, kc = tid >> 6;
    const float* W = tp_W + l * HH * HH;
    float a = 0.0f;
#pragma unroll 8
    for (int k0 = 0; k0 < 64; k0++) {
        int k = kc * 64 + k0;
        a = fmaf(es[k], W[k * HH + cb + col], a);
    }
    part[kc][col] = a;
    __syncthreads();
    if (kc == 0) {
        float o = part[0][col] + part[1][col] + part[2][col] + part[3][col]
                + tp_b[l * HH + cb + col];
        tbias_out[l * (BB * HH) + b * HH + cb + col] = o;
    }
}

// ---------- 3) adj_t (bf16) + inverse row abs-sum (fp32) ----------
__global__ __launch_bounds__(256) void adj_kernel(
    const float* __restrict__ adj0, const float* __restrict__ noise,
    const int* __restrict__ t, const float* __restrict__ sched,
    ushort_t* __restrict__ adjt_bf, float* __restrict__ invrs) {
    __shared__ float red[4];
    const int bid = blockIdx.x;          // b*512 + i
    const int b = bid >> 9;
    const int ts = t[b];
    const float sab = sched[ts], som = sched[100 + ts];
    const size_t base = (size_t)bid * NN;
    const int tid = threadIdx.x;
    float s = 0.0f;
#pragma unroll
    for (int jj = 0; jj < 2; jj++) {
        int j = tid + jj * 256;
        float a = sab * adj0[base + j] + som * noise[base + j];
        adjt_bf[base + j] = f2bf(a);
        s += fabsf(a);
    }
    s = block_reduce_sum256(s, red);
    if (tid == 0) invrs[bid] = 1.0f / (s + 1.0f);
}

// ---------- 4) weight transpose+convert: W (RxC f32) -> WT (CxR bf16) ----------
__global__ __launch_bounds__(256) void wcvt_kernel(
    const float* __restrict__ ip_W, const float* __restrict__ msg_W,
    const float* __restrict__ upd_W,
    ushort_t* __restrict__ ipWT, ushort_t* __restrict__ msgWT,
    ushort_t* __restrict__ updWT) {
    const int z = blockIdx.z;
    const float* src; ushort_t* dst; int R;
    if (z == 0)      { src = ip_W;                          dst = ipWT;                       R = 512; }
    else if (z <= 4) { src = msg_W + (z - 1) * 65536;       dst = msgWT + (z - 1) * 65536;    R = 256; }
    else             { src = upd_W + (z - 5) * 131072;      dst = updWT + (z - 5) * 131072;   R = 512; }
    const int r0 = blockIdx.y * 32, c0 = blockIdx.x * 32;
    if (r0 >= R) return;
    __shared__ float T[32][33];
    const int tr = threadIdx.x >> 5, tc = threadIdx.x & 31;
#pragma unroll
    for (int s = 0; s < 32; s += 8)
        T[tr + s][tc] = src[(size_t)(r0 + tr + s) * 256 + c0 + tc];
    __syncthreads();
#pragma unroll
    for (int s = 0; s < 32; s += 8)
        dst[(size_t)(c0 + tr + s) * R + r0 + tc] = f2bf(T[tc][tr + s]);
}

// ---------- 5) bf16 MFMA GEMM: tile 128x64, grid (M/128, 256/64) = 512 blocks ----------
// 4 waves in 2x2; each wave 64x32 (acc 4x2 of 16x16x32 MFMA).
// Staging: global_load_lds width=16, XOR-swizzled 16B chunks within 64B LDS rows.
// BT[n][k] transposed B, bstride per 512-row batch. A2: concat switch at k=256.
// Epilogue: v = acc*(scale?scale[row]:1) + bias[col] (+ tbias + resid). Outputs:
//   Cf (fp32) / Cb (bf16) row-major, or CbT (bf16, per-batch transposed via LDS).
__global__ __launch_bounds__(256, 2) void gemm_bf16(
    int K,
    const ushort_t* __restrict__ A, int lda, const ushort_t* __restrict__ A2,
    const ushort_t* __restrict__ BT, int ldbt, long long bstride,
    const float* __restrict__ bias, const float* __restrict__ scale,
    const float* __restrict__ tbias, const ushort_t* __restrict__ resid,
    float* __restrict__ Cf, ushort_t* __restrict__ Cb, ushort_t* __restrict__ CbT) {
    __shared__ ushort_t As[128 * 32];
    __shared__ ushort_t Bs[64 * 32];
    __shared__ ushort_t Ts[64 * 136];
    const int row0 = blockIdx.x * 128;
    const int n0 = blockIdx.y * 64;
    const int tid = threadIdx.x;
    const int lane = tid & 63;
    const int w = tid >> 6;
    const int l15 = lane & 15, quad = lane >> 4;
    const int wm = (w >> 1) * 64, wn = (w & 1) * 32;
    const ushort_t* Bp = BT + (size_t)(row0 >> 9) * (size_t)bstride;

    const int srow = lane >> 2;                               // row within 16-row DMA chunk
    const int gkoff = (((lane & 3) ^ (lane >> 4)) << 3);      // swizzled global k-offset
    const int swz = ((quad ^ ((l15 >> 2) & 3)) << 3);         // frag-read k-offset

    floatx4 acc[4][2];
#pragma unroll
    for (int i = 0; i < 4; i++)
#pragma unroll
        for (int j = 0; j < 2; j++) {
            acc[i][j][0] = 0.0f; acc[i][j][1] = 0.0f;
            acc[i][j][2] = 0.0f; acc[i][j][3] = 0.0f;
        }

    for (int kc = 0; kc < K; kc += 32) {
        const ushort_t* Ause = A; int kk = kc;
        if (A2 && kc >= 256) { Ause = A2; kk = kc - 256; }
        // A: 128 rows -> 2 DMA rounds per wave
#pragma unroll
        for (int r = 0; r < 2; r++) {
            const int lbase = (r * 4 + w) * 16;
            const ushort_t* gpA = Ause + (size_t)(row0 + lbase + srow) * lda + kk + gkoff;
            __builtin_amdgcn_global_load_lds((glb_u32p)(const void*)gpA,
                                             (lds_u32p)(void*)&As[lbase * 32], 16, 0, 0);
        }
        // B: 64 rows -> 1 DMA round per wave
        {
            const int lbase = w * 16;
            const ushort_t* gpB = Bp + (size_t)(n0 + lbase + srow) * ldbt + kc + gkoff;
            __builtin_amdgcn_global_load_lds((glb_u32p)(const void*)gpB,
                                             (lds_u32p)(void*)&Bs[lbase * 32], 16, 0, 0);
        }
        __syncthreads();

        short8 af[4], bfr[2];
#pragma unroll
        for (int tm = 0; tm < 4; tm++)
            af[tm] = *(const short8*)&As[(wm + tm * 16 + l15) * 32 + swz];
#pragma unroll
        for (int tn = 0; tn < 2; tn++)
            bfr[tn] = *(const short8*)&Bs[(wn + tn * 16 + l15) * 32 + swz];
#pragma unroll
        for (int tm = 0; tm < 4; tm++)
#pragma unroll
            for (int tn = 0; tn < 2; tn++)
                acc[tm][tn] = __builtin_amdgcn_mfma_f32_16x16x32_bf16(
                    af[tm], bfr[tn], acc[tm][tn], 0, 0, 0);
        __syncthreads();
    }

    if (CbT) {
        // transposed epilogue: acc -> Ts[col][m] -> coalesced per-batch store
#pragma unroll
        for (int tm = 0; tm < 4; tm++)
#pragma unroll
            for (int tn = 0; tn < 2; tn++)
#pragma unroll
                for (int r = 0; r < 4; r++) {
                    const int ml = wm + tm * 16 + quad * 4 + r;
                    const int cl = wn + tn * 16 + l15;
                    float v = acc[tm][tn][r];
                    if (bias) v += bias[n0 + cl];
                    Ts[cl * 136 + ml] = f2bf(v);
                }
        __syncthreads();
        const int cl = tid >> 2, ch = (tid & 3) * 32;
        const int b = row0 >> 9;
        ushort_t* dst = CbT + (size_t)b * NN * HH + (size_t)(n0 + cl) * NN + (row0 & 511) + ch;
        uint4 u0 = *(const uint4*)&Ts[cl * 136 + ch];
        uint4 u1 = *(const uint4*)&Ts[cl * 136 + ch + 8];
        uint4 u2 = *(const uint4*)&Ts[cl * 136 + ch + 16];
        uint4 u3 = *(const uint4*)&Ts[cl * 136 + ch + 24];
        *(uint4*)(dst)      = u0;
        *(uint4*)(dst + 8)  = u1;
        *(uint4*)(dst + 16) = u2;
        *(uint4*)(dst + 24) = u3;
        return;
    }

#pragma unroll
    for (int tm = 0; tm < 4; tm++)
#pragma unroll
        for (int tn = 0; tn < 2; tn++) {
#pragma unroll
            for (int r = 0; r < 4; r++) {
                const int row = row0 + wm + tm * 16 + quad * 4 + r;
                const int col = n0 + wn + tn * 16 + l15;
                float v = acc[tm][tn][r];
                if (scale) v *= scale[row];
                if (bias) v += bias[col];
                if (tbias) v += tbias[((row >> 9) << 8) + col] + bf2f(resid[(size_t)row * HH + col]);
                if (Cf) Cf[(size_t)row * HH + col] = v;
                if (Cb) Cb[(size_t)row * HH + col] = f2bf(v);
            }
        }
}

// ---------- 6) layernorm: h_bf = bf16(LN(pre) * g + b) ----------
__global__ __launch_bounds__(256) void ln_kernel(
    const float* __restrict__ pre, const float* __restrict__ g,
    const float* __restrict__ b, ushort_t* __restrict__ h_bf) {
    __shared__ float red[4];
    const size_t base = (size_t)blockIdx.x * HH;
    const int tid = threadIdx.x;
    float x = pre[base + tid];
    float mu = block_reduce_sum256(x, red) * (1.0f / HH);
    float d = x - mu;
    float var = block_reduce_sum256(d * d, red) * (1.0f / HH);
    h_bf[base + tid] = f2bf(d * rsqrtf(var + 1e-5f) * g[tid] + b[tid]);
}

// ---------- 7) partial h_graph sums ----------
__global__ __launch_bounds__(256) void psum_kernel(
    const ushort_t* __restrict__ h_bf, float* __restrict__ partial) {
    const int b = blockIdx.x, ch = blockIdx.y, tid = threadIdx.x;
    const ushort_t* hp = h_bf + ((size_t)b * NN + ch * 32) * HH;
    float s = 0.0f;
#pragma unroll
    for (int i = 0; i < 32; i++) s += bf2f(hp[i * HH + tid]);
    partial[(((size_t)b * 16 + ch) << 8) + tid] = s;
}

// ---------- 8) h_graph reduce + first proj + silu -> sT[h][b] ----------
__global__ __launch_bounds__(256) void final_kernel(
    const float* __restrict__ partial, const float* __restrict__ op_W1,
    const float* __restrict__ op_b1, float* __restrict__ sT) {
    int b = blockIdx.x, tid = threadIdx.x;
    __shared__ float hg[HH];
    float acc = 0.0f;
#pragma unroll
    for (int c = 0; c < 16; c++) acc += partial[(((size_t)b * 16 + c) << 8) + tid];
    hg[tid] = acc;
    __syncthreads();
    float o = op_b1[tid];
#pragma unroll 8
    for (int k = 0; k < HH; k++) o = fmaf(hg[k], op_W1[k * HH + tid], o);
    sT[tid * BB + b] = o / (1.0f + expf(-o));
}

// ---------- 9) fused second proj + triu target + MSE (NE = 511*256 exactly) ----------
__global__ __launch_bounds__(256) void loss_kernel(
    const float* __restrict__ sT, const float* __restrict__ op_W2,
    const float* __restrict__ op_b2, const float* __restrict__ noise,
    float* __restrict__ out) {
    __shared__ float red[4];
    const int tid = threadIdx.x;
    const int e = blockIdx.x * 256 + tid;
    float lsum = 0.0f;
    float acc[32];
#pragma unroll
    for (int b = 0; b < 32; b++) acc[b] = 0.0f;
    const float* w2 = op_W2 + e;
#pragma unroll 8
    for (int h = 0; h < 256; h++) {
        float wv = w2[(size_t)h * NE];
        const float* sr = sT + h * BB;   // block-uniform -> s_load
#pragma unroll
        for (int b = 0; b < 32; b++) acc[b] = fmaf(sr[b], wv, acc[b]);
    }
    int i = (int)((1023.0 - sqrt(1046529.0 - 8.0 * (double)e)) * 0.5);
    if (i < 0) i = 0;
    if (i > 510) i = 510;
    while (i > 0 && (i * (1023 - i)) / 2 > e) --i;
    while (((i + 1) * (1022 - i)) / 2 <= e) ++i;
    int j = i + 1 + (e - (i * (1023 - i)) / 2);
    const float pb = op_b2[e];
    const float* np = noise + (size_t)i * NN + j;
#pragma unroll
    for (int b = 0; b < 32; b++) {
        float d = acc[b] + pb - np[(size_t)b * NN * NN];
        lsum += d * d;
    }
    lsum *= (1.0f / (32.0f * (float)NE));
    lsum = block_reduce_sum256(lsum, red);
    if (tid == 0) atomicAdd(out, lsum);
}

// ---------- launch ----------
extern "C" void kernel_launch(void* const* d_in, const int* in_sizes, int n_in,
                              void* d_out, int out_size, void* d_ws, size_t ws_size,
                              hipStream_t stream) {
    const float* adj0  = (const float*)d_in[0];
    const float* noise = (const float*)d_in[1];
    const float* te_W1 = (const float*)d_in[2];
    const float* te_b1 = (const float*)d_in[3];
    const float* te_W2 = (const float*)d_in[4];
    const float* te_b2 = (const float*)d_in[5];
    const float* ip_W  = (const float*)d_in[6];
    const float* ip_b  = (const float*)d_in[7];
    const float* msg_W = (const float*)d_in[8];
    const float* msg_b = (const float*)d_in[9];
    const float* upd_W = (const float*)d_in[10];
    const float* upd_b = (const float*)d_in[11];
    const float* ln_g  = (const float*)d_in[12];
    const float* ln_b  = (const float*)d_in[13];
    const float* tp_W  = (const float*)d_in[14];
    const float* tp_b  = (const float*)d_in[15];
    const float* op_W1 = (const float*)d_in[16];
    const float* op_b1 = (const float*)d_in[17];
    const float* op_W2 = (const float*)d_in[18];
    const float* op_b2 = (const float*)d_in[19];
    const int*   t     = (const int*)d_in[20];
    float* out = (float*)d_out;

    float* ws = (float*)d_ws;
    float* sched   = ws;                    // 256
    float* tbias   = ws + 256;              // 32768
    float* invrs   = ws + 33024;            // 16384
    float* sbuf    = ws + 49408;            // 8192 (sT: 256x32)
    float* embb    = ws + 57600;            // 8192 (emb: 32x256)
    float* partial = ws + 65792;            // 131072
    float* pre     = ws + 196864;           // 4194304
    ushort_t* bfb  = (ushort_t*)(ws + 4391168);
    ushort_t* adjt_bf = bfb;                // 8388608 ushorts
    ushort_t* h_bf    = bfb + 8388608;      // 4194304
    ushort_t* msg_bf  = bfb + 12582912;     // 4194304
    ushort_t* hmT_bf  = bfb + 16777216;     // 4194304
    ushort_t* ipWT    = bfb + 20971520;     // 131072
    ushort_t* msgWT   = bfb + 21102592;     // 262144
    ushort_t* updWT   = bfb + 21364736;     // 524288

    init_kernel<<<1, 128, 0, stream>>>(sched, out);
    wcvt_kernel<<<dim3(8, 16, 9), 256, 0, stream>>>(ip_W, msg_W, upd_W, ipWT, msgWT, updWT);
    temb1_kernel<<<dim3(32, 4), 256, 0, stream>>>(te_W1, te_b1, te_W2, te_b2, t, embb);
    temb2_kernel<<<dim3(32, 16), 256, 0, stream>>>(embb, tp_W, tp_b, tbias);
    adj_kernel<<<BB * NN, 256, 0, stream>>>(adj0, noise, t, sched, adjt_bf, invrs);

    dim3 ggrid(128, 4);   // M=16384/128, N=256/64 -> 512 blocks (2/CU)
    // h = bf16(adj_t @ ip_W + ip_b)
    gemm_bf16<<<ggrid, 256, 0, stream>>>(512, adjt_bf, 512, nullptr,
                                         ipWT, 512, 0,
                                         ip_b, nullptr, nullptr, nullptr,
                                         nullptr, h_bf, nullptr);
    for (int l = 0; l < 4; l++) {
        // hmT[b] = (h @ msg_W[l] + msg_b[l])^T   (transposed epilogue)
        gemm_bf16<<<ggrid, 256, 0, stream>>>(256, h_bf, 256, nullptr,
                                             msgWT + l * 65536, 256, 0,
                                             msg_b + l * HH, nullptr, nullptr, nullptr,
                                             nullptr, nullptr, hmT_bf);
        // msg = bf16(rowscale * (adj_t @ hm[b]))
        gemm_bf16<<<ggrid, 256, 0, stream>>>(512, adjt_bf, 512, nullptr,
                                             hmT_bf, 512, (long long)(HH * NN),
                                             nullptr, invrs, nullptr, nullptr,
                                             nullptr, msg_bf, nullptr);
        // pre = h@updW[:256] + msg@updW[256:] + upd_b + t_bias + h
        gemm_bf16<<<ggrid, 256, 0, stream>>>(512, h_bf, 256, msg_bf,
                                             updWT + l * 131072, 512, 0,
                                             upd_b + l * HH, nullptr,
                                             tbias + l * BB * HH, h_bf,
                                             pre, nullptr, nullptr);
        // h = bf16(LN(pre)*g + b)
        ln_kernel<<<BB * NN, 256, 0, stream>>>(pre, ln_g + l * HH, ln_b + l * HH, h_bf);
    }
    psum_kernel<<<dim3(32, 16), 256, 0, stream>>>(h_bf, partial);
    final_kernel<<<32, 256, 0, stream>>>(partial, op_W1, op_b1, sbuf);
    loss_kernel<<<511, 256, 0, stream>>>(sbuf, op_W2, op_b2, noise, out);
}